// Round 11
// baseline (861.243 us; speedup 1.0000x reference)
//
#include <hip/hip_runtime.h>
#include <math.h>

#define N16 1600
#define M 32
#define XSZ 51200
#define LDSF 8448
#define WST 68
#define BIS_IT 28
#define EPSF 1e-12f
#define NPH 30   // 0 resize+zero | 1 prep | 2 degree | 3-12 MV1-10 | 13 gram |
                 // 14 apply | 15-24 MV11-20 | 25 gram | 26 apply | 27 MV21 |
                 // 28 gram | 29 rr

// ---------------- device-scope (L3-level) access helpers --------------------
__device__ __forceinline__ float ldg_dev(const float* p) {
  return __hip_atomic_load(p, __ATOMIC_RELAXED, __HIP_MEMORY_SCOPE_AGENT);
}
__device__ __forceinline__ void stg_dev(float* p, float v) {
  __hip_atomic_store(p, v, __ATOMIC_RELAXED, __HIP_MEMORY_SCOPE_AGENT);
}
__device__ __forceinline__ void stg_devi(int* p, int v) {
  __hip_atomic_store(p, v, __ATOMIC_RELAXED, __HIP_MEMORY_SCOPE_AGENT);
}

// ---------------- wave reductions -------------------------------------------
__device__ __forceinline__ float wred(float v) {
#pragma unroll
  for (int o = 32; o; o >>= 1) v += __shfl_xor(v, o, 64);
  return v;
}
__device__ __forceinline__ float wredmin(float v) {
#pragma unroll
  for (int o = 32; o; o >>= 1) v = fminf(v, __shfl_xor(v, o, 64));
  return v;
}
__device__ __forceinline__ float wredmax(float v) {
#pragma unroll
  for (int o = 32; o; o >>= 1) v = fmaxf(v, __shfl_xor(v, o, 64));
  return v;
}

// ---------------- spread monotonic grid barrier (250 blocks fixed) ----------
// barr[lane*32], lane=bx&15 (16 lines 128B apart); master at +512; gen at +544.
// Counters never reset: block arrives when its line reaches (s+1)*quota.
__device__ __forceinline__ void grid_barrier(unsigned* barr, int s, int bx, int t) {
  __threadfence_block();
  __syncthreads();
  if (t == 0) {
    unsigned* gen = barr + 544;
    const int lane = bx & 15;
    const unsigned quota = 15u + ((lane < 10) ? 1u : 0u);  // 250 = 10*16 + 6*15
    unsigned a = __hip_atomic_fetch_add(barr + lane * 32, 1u, __ATOMIC_RELAXED,
                                        __HIP_MEMORY_SCOPE_AGENT);
    bool done = false;
    if (a + 1u == (unsigned)(s + 1) * quota) {
      unsigned m = __hip_atomic_fetch_add(barr + 512, 1u, __ATOMIC_RELAXED,
                                          __HIP_MEMORY_SCOPE_AGENT);
      if (m + 1u == (unsigned)(s + 1) * 16u) {
        __hip_atomic_store(gen, (unsigned)(s + 1), __ATOMIC_RELAXED,
                           __HIP_MEMORY_SCOPE_AGENT);
        done = true;
      }
    }
    if (!done)
      while ((int)__hip_atomic_load(gen, __ATOMIC_RELAXED,
                                    __HIP_MEMORY_SCOPE_AGENT) <= s)
        __builtin_amdgcn_s_sleep(2);
  }
  __syncthreads();
}

// ---------------- phase: resize (bx<168) + zero (bx>=168) -------------------
__device__ void taps1d(int o, int* lo, int* hi, float* wsum, float w[8]) {
  int l = 4 * o - 2, h = 4 * o + 5;
  if (l < 0) l = 0;
  if (h > 159) h = 159;
  float c = 4.f * o + 1.5f, s = 0.f;
  for (int x = l; x <= h; ++x) {
    float ww = 1.f - fabsf((float)x - c) * 0.25f;
    w[x - l] = ww;
    s += ww;
  }
  *lo = l; *hi = h; *wsum = s;
}

__device__ void resize_phase(const float* __restrict__ in, float* __restrict__ rz,
                             int bx, int t) {
  int map = bx / 7;
  int o = (bx % 7) * 256 + t;
  if (o >= N16) return;
  int oy = o / 40, ox = o % 40;
  int ly, hy, lx, hx; float sy, sx; float wy[8], wx[8];
  taps1d(oy, &ly, &hy, &sy, wy);
  taps1d(ox, &lx, &hx, &sx, wx);
  const float* src = in + (size_t)map * 160 * 160;
  float acc = 0.f;
  for (int y = ly; y <= hy; ++y) {
    float a = 0.f;
    const float* row = src + y * 160;
    for (int x = lx; x <= hx; ++x) a += wx[x - lx] * row[x];
    acc += wy[y - ly] * a;
  }
  stg_dev(rz + map * N16 + o, acc / (sy * sx));
}

__device__ void zero_phase(float* __restrict__ XB, float* __restrict__ GPb,
                           int mode, int bx, int t) {
  int tid = (bx - 168) * 256 + t;
  const int stride = 82 * 256;
  if (mode != 2) {  // mode2 slabs are written with plain stores; no zero needed
    float* base = XB + (size_t)(mode ? 3 : 1) * XSZ;
    size_t len = (size_t)(mode ? 21 : 3) * XSZ;
    for (size_t i = tid; i < len; i += stride) stg_dev(base + i, 0.f);
  }
  for (int i = tid; i < 3072; i += stride) stg_dev(GPb + i, 0.f);
}

// ---------------- phase: prep (bx<23) ---------------------------------------
__device__ void prep_phase(const float* __restrict__ rz, float* __restrict__ F,
                           int* __restrict__ flags, float* LDSu, int bx, int t) {
  int* sp = (int*)LDSu;
  int* sn = sp + 256;
  if (bx < 16) {
    int b = bx >> 1, c = bx & 1;
    const float* m = rz + (b * 3 + c) * N16;
    int cp = 0, cn = 0;
    for (int o = t; o < N16; o += 256) {
      float v = m[o];
      cp += (v > 0.f);
      cn += (v < 0.f);
    }
    sp[t] = cp; sn[t] = cn;
    __syncthreads();
    for (int s = 128; s > 0; s >>= 1) {
      if (t < s) { sp[t] += sp[t + s]; sn[t] += sn[t + s]; }
      __syncthreads();
    }
    if (t == 0) stg_devi(flags + bx, (sp[0] == 0 || sn[0] == 0) ? 1 : 0);
  } else if (bx < 23) {
    int n = (bx - 16) * 256 + t;
    if (n < N16) {
      float x = rz[n], y = rz[N16 + n], z = rz[2 * N16 + n];
      float nrm = sqrtf(x * x + y * y + z * z);
      float s = 1.f / fmaxf(nrm, EPSF);
      stg_dev(F + n * 3 + 0, x * s);
      stg_dev(F + n * 3 + 1, y * s);
      stg_dev(F + n * 3 + 2, z * s);
    }
  }
}

// ---------------- phase: degree + G4 + X0 init (bx<100) ---------------------
__device__ void degree_phase(const float* __restrict__ F, float* __restrict__ R,
                             float* __restrict__ G4f, float* __restrict__ X0,
                             float* LDSu, int bx, int t) {
  float* Fl = LDSu;          // 4800
  float* red = LDSu + 4800;  // 256
  for (int s = t; s < 4800; s += 256) Fl[s] = F[s];
  __syncthreads();
  int rl = t >> 4, jt = t & 15;
  int i = bx * 16 + rl;
  float fx = Fl[i * 3], fy = Fl[i * 3 + 1], fz = Fl[i * 3 + 2];
  float s = 0.f;
  for (int j = jt; j < N16; j += 16) {
    float w = fx * Fl[j * 3] + fy * Fl[j * 3 + 1] + fz * Fl[j * 3 + 2];
    if (w > 0.f) s += w;
  }
  red[t] = s;
  __syncthreads();
  for (int st = 8; st > 0; st >>= 1) {
    if (jt < st) red[t] += red[t + st];
    __syncthreads();
  }
  if (jt == 0) {
    float d = red[t];
    if (d < EPSF) d = 1.f;
    float r = rsqrtf(d);
    stg_dev(R + i, r);
    stg_dev(G4f + i * 4 + 0, r * fx);
    stg_dev(G4f + i * 4 + 1, r * fy);
    stg_dev(G4f + i * 4 + 2, r * fz);
    stg_dev(G4f + i * 4 + 3, 0.f);
  }
  for (int e = t; e < 512; e += 256) {
    int n = bx * 16 + (e >> 5);
    int k = e & 31;
    unsigned u = ((unsigned)n * 2654435761u) ^ ((unsigned)k * 0x9E3779B9u);
    u = u * 1664525u + 1013904223u;
    u ^= u >> 16; u *= 2246822519u; u ^= u >> 13;
    stg_dev(X0 + n * M + k, ((float)(u >> 8) * (1.f / 8388608.f)) - 1.f);
  }
}

// ---------------- phase: MV -------------------------------------------------
// npin partial buffers (stride XSZ) summed on load; output either plain sc1
// store into own slab (oslab: Xout + jp*XSZ) or atomicAdd into single buffer.
__device__ void mv_phase(const float* __restrict__ F, const float4* __restrict__ G4,
                         const float* __restrict__ R, const float* __restrict__ Xin,
                         int npin, int cach, float* __restrict__ Xout, int oslab,
                         float* __restrict__ Znext, int rb, int jp,
                         float* LDSu, int t) {
  float* XsT = LDSu;          // [32][WST]
  float* Ws  = LDSu + 2176;   // [32][WST]
  float* Red = LDSu + 4352;   // [4][1024]
  const int rg = t & 7, kg = (t >> 3) & 7, jg = t >> 6;
  const int i0 = rb * 32;
  const int jlo = jp * 320;
  const int il = t & 31;
  const float fx = F[(i0 + il) * 3], fy = F[(i0 + il) * 3 + 1],
              fz = F[(i0 + il) * 3 + 2];
  float acc[4][4];
#pragma unroll
  for (int r = 0; r < 4; ++r)
#pragma unroll
    for (int kk = 0; kk < 4; ++kk) acc[r][kk] = 0.f;

  for (int c = 0; c < 5; ++c) {
    const int jbase = jlo + c * 64;
    __syncthreads();
    if (cach) {
#pragma unroll
      for (int it = 0; it < 2; ++it) {
        int e = it * 256 + t;           // 0..511
        int row = e >> 3, q = e & 7;
        const float4* p4 = (const float4*)Xin + (size_t)(jbase + row) * 8 + q;
        float4 v = p4[0];
        for (int p = 1; p < npin; ++p) {
          float4 a = p4[(size_t)p * (XSZ / 4)];
          v.x += a.x; v.y += a.y; v.z += a.z; v.w += a.w;
        }
        XsT[(q * 4 + 0) * WST + row] = v.x;
        XsT[(q * 4 + 1) * WST + row] = v.y;
        XsT[(q * 4 + 2) * WST + row] = v.z;
        XsT[(q * 4 + 3) * WST + row] = v.w;
      }
    } else {
#pragma unroll
      for (int it = 0; it < 2; ++it) {
        int e = it * 256 + t;
        int row = e >> 3, q = e & 7;
        const float* p = Xin + (size_t)(jbase + row) * 32 + q * 4;
        float v0 = ldg_dev(p + 0);
        float v1 = ldg_dev(p + 1);
        float v2 = ldg_dev(p + 2);
        float v3 = ldg_dev(p + 3);
        XsT[(q * 4 + 0) * WST + row] = v0;
        XsT[(q * 4 + 1) * WST + row] = v1;
        XsT[(q * 4 + 2) * WST + row] = v2;
        XsT[(q * 4 + 3) * WST + row] = v3;
      }
    }
#pragma unroll
    for (int it = 0; it < 8; ++it) {
      int jl = it * 8 + (t >> 5);
      float4 g = G4[jbase + jl];
      Ws[il * WST + jl] = fmaxf(fx * g.x + fy * g.y + fz * g.z, 0.f);
    }
    __syncthreads();
#pragma unroll
    for (int q = 0; q < 4; ++q) {
      const int jq = (jg * 4 + q) * 4;
      float4 wv[4], xv[4];
#pragma unroll
      for (int r = 0; r < 4; ++r)
        wv[r] = *(const float4*)&Ws[(rg + 8 * r) * WST + jq];
#pragma unroll
      for (int kk = 0; kk < 4; ++kk)
        xv[kk] = *(const float4*)&XsT[(kg + 8 * kk) * WST + jq];
#pragma unroll
      for (int r = 0; r < 4; ++r)
#pragma unroll
        for (int kk = 0; kk < 4; ++kk)
          acc[r][kk] += wv[r].x * xv[kk].x + wv[r].y * xv[kk].y +
                        wv[r].z * xv[kk].z + wv[r].w * xv[kk].w;
    }
  }
  __syncthreads();
#pragma unroll
  for (int r = 0; r < 4; ++r)
#pragma unroll
    for (int kk = 0; kk < 4; ++kk)
      Red[jg * 1024 + (rg + 8 * r) * 32 + (kg + 8 * kk)] = acc[r][kk];
  __syncthreads();
#pragma unroll
  for (int it = 0; it < 4; ++it) {
    int o = it * 256 + t;
    int ilw = o >> 5, k = o & 31;
    int gi = i0 + ilw;
    float sv = Red[o] + Red[1024 + o] + Red[2048 + o] + Red[3072 + o];
    float val = 0.5f * R[gi] * sv;
    if (jp == 0) {
      float xi = 0.f;
      if (cach) {
        for (int p = 0; p < npin; ++p) xi += Xin[(size_t)p * XSZ + gi * 32 + k];
      } else {
        xi = ldg_dev(Xin + (size_t)gi * 32 + k);
      }
      val += 0.5f * xi;
    }
    if (oslab) stg_dev(Xout + (size_t)jp * XSZ + gi * 32 + k, val);
    else atomicAdd(Xout + (size_t)gi * 32 + k, val);
  }
  if (Znext && jp == 1) {
#pragma unroll
    for (int it = 0; it < 4; ++it)
      stg_dev(Znext + (size_t)i0 * 32 + it * 256 + t, 0.f);
  }
}

// ---------------- phase: gram (bx<25) ---------------------------------------
__device__ void gram_phase(const float* __restrict__ Xa, int npa, int ca,
                           const float* __restrict__ Xb, int npb, int cb,
                           float* __restrict__ GP, float* LDSu, int bx, int t) {
  float* sA = LDSu;
  float* sB = LDSu + 2048;
  int j0 = bx * 64;
  for (int s = t; s < 64 * M; s += 256) {
    size_t idx = (size_t)j0 * M + s;
    float a = ca ? Xa[idx] : ldg_dev(Xa + idx);
    for (int p = 1; p < npa; ++p) a += Xa[(size_t)p * XSZ + idx];
    float b = cb ? Xb[idx] : ldg_dev(Xb + idx);
    for (int p = 1; p < npb; ++p) b += Xb[(size_t)p * XSZ + idx];
    sA[s] = a; sB[s] = b;
  }
  __syncthreads();
  for (int s = 0; s < 4; ++s) {
    int e = s * 256 + t;
    int a = e >> 5, b = e & 31;
    float sum = 0.f;
    for (int jl = 0; jl < 64; ++jl) sum += sA[jl * M + a] * sB[jl * M + b];
    atomicAdd(GP + e, sum);
  }
}

// ---------------- phase: apply (bx<200): chol + register trisolve -----------
__device__ void apply_phase(const float* __restrict__ GP,
                            const float* __restrict__ Xin, int npin, int cach,
                            float* __restrict__ Xout, float* LDSu, int bx, int t) {
  float* Gm = LDSu;  // 32*33
  for (int e = t; e < 1024; e += 256)
    Gm[(e >> 5) * 33 + (e & 31)] = ldg_dev(GP + e);
  const int r = t >> 5, l = t & 31;
  const int row = bx * 8 + r;
  float x;
  if (cach) {
    x = Xin[(size_t)row * M + l];
    for (int p = 1; p < npin; ++p) x += Xin[(size_t)p * XSZ + row * M + l];
  } else {
    x = ldg_dev(Xin + (size_t)row * M + l);
  }
  __syncthreads();
  for (int k = 0; k < 32; ++k) {
    if (t == 0) Gm[k * 33 + k] = sqrtf(fmaxf(Gm[k * 33 + k], 1e-30f));
    __syncthreads();
    float piv = Gm[k * 33 + k];
    if (t > k && t < 32) Gm[t * 33 + k] /= piv;
    __syncthreads();
    for (int e = t; e < 1024; e += 256) {
      int i = e >> 5, j = e & 31;
      if (i > k && j > k && j <= i) Gm[i * 33 + j] -= Gm[i * 33 + k] * Gm[j * 33 + k];
    }
    __syncthreads();
  }
  const int half = t & 32;
  float y = 0.f;
  for (int k = 0; k < 32; ++k) {
    float gkl = Gm[k * 33 + l];
    float contrib = (l < k) ? y * gkl : 0.f;
#pragma unroll
    for (int o = 16; o; o >>= 1) contrib += __shfl_xor(contrib, o, 64);
    float xk = __shfl(x, half + k, 64);
    float yk = (xk - contrib) / Gm[k * 33 + k];
    if (l == k) y = yk;
  }
  stg_dev(Xout + (size_t)row * M + l, y);
}

// ---------------- phase: rr (bx==0) -----------------------------------------
__device__ void rr_phase(const float* __restrict__ GP,
                         const int* __restrict__ flags,
                         const int* __restrict__ Kptr,
                         float* __restrict__ out, float* Ph, int t) {
  float* Bs   = Ph;
  float* part = Ph + 1056;
  float* vvs  = Ph + 2080;
  float* uus  = Ph + 2112;
  float* dd   = Ph + 2144;
  float* ee   = Ph + 2176;
  float* ee2  = Ph + 2208;
  float* evs  = Ph + 2240;
  float* shs  = Ph + 2272;
  for (int e = t; e < 1024; e += 256) part[e] = ldg_dev(GP + e);
  __syncthreads();
  for (int e = t; e < 1024; e += 256) {
    int i = e >> 5, j = e & 31;
    Bs[i * 33 + j] = 0.5f * (part[e] + part[j * 32 + i]);
  }
  __syncthreads();
  for (int k = 0; k <= 29; ++k) {
    const int m = 31 - k;
    if (t < 64) {
      float xi = (t < m) ? Bs[(k + 1 + t) * 33 + k] : 0.f;
      float nx2 = wred(xi * xi);
      if (t == 0) { shs[0] = nx2; shs[1] = Bs[(k + 1) * 33 + k]; }
    }
    __syncthreads();
    float nx2 = shs[0], x0 = shs[1];
    if (nx2 < 1e-28f) {
      if (t == 0) ee[k] = x0;
      __syncthreads();
      continue;
    }
    if (t < 32) {
      float alpha = (x0 >= 0.f) ? -sqrtf(nx2) : sqrtf(nx2);
      float h = nx2 - alpha * x0;
      float xi = (t < m) ? Bs[(k + 1 + t) * 33 + k] : 0.f;
      float vi = (t == 0) ? (xi - alpha) : xi;
      vvs[t] = (t < m) ? vi : 0.f;
      if (t == 0) { ee[k] = alpha; shs[2] = h; }
    }
    __syncthreads();
    {
      int i = t >> 3, s = t & 7;
      float p = 0.f;
      if (i < m) {
        const float* rowp = &Bs[(k + 1 + i) * 33 + (k + 1)];
        for (int j = s; j < m; j += 8) p += rowp[j] * vvs[j];
      }
      part[t] = p;
    }
    __syncthreads();
    if (t < 64) {
      float h = shs[2];
      float pi = 0.f;
      if (t < 32) {
#pragma unroll
        for (int s = 0; s < 8; ++s) pi += part[t * 8 + s];
        pi /= h;
      }
      float vip = (t < 32) ? vvs[t] * pi : 0.f;
      float vp = wred(vip);
      float Kc = vp / (2.f * h);
      if (t < 32) uus[t] = (t < m) ? (pi - Kc * vvs[t]) : 0.f;
    }
    __syncthreads();
    for (int e = t; e < 1024; e += 256) {
      int i = e >> 5, j = e & 31;
      if (i < m && j < m)
        Bs[(k + 1 + i) * 33 + (k + 1 + j)] -= vvs[i] * uus[j] + uus[i] * vvs[j];
    }
    __syncthreads();
  }
  if (t < 32) dd[t] = Bs[t * 33 + t];
  if (t == 0) { ee[30] = Bs[31 * 33 + 30]; ee[31] = 0.f; }
  __syncthreads();
  if (t < 32) ee2[t] = (t < 31) ? ee[t] * ee[t] : 0.f;
  __syncthreads();
  if (t < 64) {
    int tt = t & 31;
    float di = dd[tt];
    float r = 0.f;
    if (tt > 0) r += fabsf(ee[tt - 1]);
    if (tt < 31) r += fabsf(ee[tt]);
    float lo = wredmin(di - r);
    float hi = wredmax(di + r);
    if (t == 0) { shs[0] = lo - 1e-6f; shs[1] = hi + 1e-6f; }
  }
  __syncthreads();
  if (t < 32) {
    float a = shs[0], b = shs[1];
    for (int it = 0; it < BIS_IT; ++it) {
      float mid = 0.5f * (a + b);
      float q = dd[0] - mid;
      int cnt = (q < 0.f) ? 1 : 0;
#pragma unroll
      for (int i = 1; i < 32; ++i) {
        float den = q;
        float ad = fabsf(den);
        den = (ad < 1e-30f) ? ((den < 0.f) ? -1e-30f : 1e-30f) : den;
        q = dd[i] - mid - ee2[i - 1] * __builtin_amdgcn_rcpf(den);
        cnt += (q < 0.f) ? 1 : 0;
      }
      if (cnt <= t) a = mid; else b = mid;
    }
    evs[t] = 0.5f * (a + b);
  }
  __syncthreads();
  if (t == 0) {
    int K = Kptr ? *Kptr : 10;
    if (K < 1) K = 10;
    if (K > 32) K = 32;
    float t12 = 0.f, t13 = 0.f, t23 = 0.f;
    for (int b = 0; b < 8; ++b) {
      float f1 = flags[b * 2 + 0] ? 1.f : 0.f;
      float f2 = flags[b * 2 + 1] ? 1.f : 0.f;
      for (int k = 0; k < K; ++k) {
        float v1 = (k == 0) ? 0.f : (k == 1 ? f1 : 1.f);
        float v2 = (k == 0) ? 0.f : (k == 1 ? f2 : 1.f);
        float m3 = 2.f - 2.f * evs[31 - k];
        t12 += (v1 - v2) * (v1 - v2);
        t13 += (v1 - m3) * (v1 - m3);
        t23 += (v2 - m3) * (v2 - m3);
      }
    }
    out[0] = 5.f * (t12 + t13 + t23) / (8.f * (float)K);
  }
}

// ---------------- unified step dispatcher -----------------------------------
__device__ __forceinline__ float* bbuf(float* XB, int mode, int m) {
  return XB + (size_t)(mode ? (2 + m) : (1 + m % 3)) * XSZ;  // modes 0/1
}
__device__ __forceinline__ float* sl(float* XB, int m) {   // mode2 slabset m
  return XB + (size_t)3 * XSZ + (size_t)(m - 1) * 5 * XSZ;
}

__device__ void do_step(int s, const float* feats, float* RZ, float* F,
                        float* G4f, float* R, int* flags, float* GPb, float* XB,
                        const int* Kptr, float* out, int mode,
                        float* LDSu, int bx, int t) {
  float* X0  = XB;
  float* XV1 = XB + (size_t)(mode ? 1 : 0) * XSZ;
  float* XV2 = XB + (size_t)(mode ? 2 : 0) * XSZ;
  const float4* G4 = (const float4*)G4f;
  const int m2 = (mode == 2);
  if (s == 0) {
    if (bx < 168) resize_phase(feats, RZ, bx, t);
    else zero_phase(XB, GPb, mode, bx, t);
    return;
  }
  if (s == 1) { prep_phase(RZ, F, flags, LDSu, bx, t); return; }
  if (s == 2) { if (bx < 100) degree_phase(F, R, G4f, X0, LDSu, bx, t); return; }
  if (s == 13) {
    if (bx < 25) {
      const float* Xa = m2 ? sl(XB, 10) : bbuf(XB, mode, 10);
      gram_phase(Xa, m2 ? 5 : 1, m2, Xa, m2 ? 5 : 1, m2, GPb, LDSu, bx, t);
    }
    return;
  }
  if (s == 14) {
    if (bx < 200)
      apply_phase(GPb, m2 ? sl(XB, 10) : bbuf(XB, mode, 10), m2 ? 5 : 1, m2,
                  XV1, LDSu, bx, t);
    return;
  }
  if (s == 25) {
    if (bx < 25) {
      const float* Xa = m2 ? sl(XB, 20) : bbuf(XB, mode, 20);
      gram_phase(Xa, m2 ? 5 : 1, m2, Xa, m2 ? 5 : 1, m2, GPb + 1024, LDSu, bx, t);
    }
    return;
  }
  if (s == 26) {
    if (bx < 200)
      apply_phase(GPb + 1024, m2 ? sl(XB, 20) : bbuf(XB, mode, 20), m2 ? 5 : 1,
                  m2, XV2, LDSu, bx, t);
    return;
  }
  if (s == 28) {
    if (bx < 25) {
      const float* Xb = m2 ? sl(XB, 21) : bbuf(XB, mode, 21);
      gram_phase(XV2, 1, m2, Xb, m2 ? 5 : 1, m2, GPb + 2048, LDSu, bx, t);
    }
    return;
  }
  if (s == 29) { if (bx == 0) rr_phase(GPb + 2048, flags, Kptr, out, LDSu, t); return; }
  // MV phases
  int m;
  if (s >= 3 && s <= 12) m = s - 2;
  else if (s >= 15 && s <= 24) m = s - 4;
  else m = 21;
  const float* Xin;
  int npin, cach, oslab;
  float* Xout;
  float* Znext = nullptr;
  if (m2) {
    cach = 1; oslab = 1;
    if (m == 1) { Xin = X0; npin = 1; }
    else if (m == 11) { Xin = XV1; npin = 1; }
    else if (m == 21) { Xin = XV2; npin = 1; }
    else { Xin = sl(XB, m - 1); npin = 5; }
    Xout = sl(XB, m);
  } else {
    npin = 1; oslab = 0; cach = (mode == 1);
    Xin = (m == 1) ? X0 : (m == 11) ? XV1 : (m == 21) ? XV2 : bbuf(XB, mode, m - 1);
    Xout = bbuf(XB, mode, m);
    if (mode == 0 && m < 21) Znext = bbuf(XB, 0, m + 1);
  }
  mv_phase(F, G4, R, Xin, npin, cach, Xout, oslab, Znext, bx / 5, bx % 5, LDSu, t);
}

__global__ void __launch_bounds__(256)
k_solve(const float* feats, float* RZ, float* F, float* G4f, float* R,
        int* flags, float* GPb, float* XB, const int* Kptr, float* out,
        int mode, unsigned* barr) {
  __shared__ __align__(16) float LDSu[LDSF];
  const int bx = blockIdx.x, t = threadIdx.x;
  for (int s = 0; s < NPH; ++s) {
    do_step(s, feats, RZ, F, G4f, R, flags, GPb, XB, Kptr, out, mode, LDSu, bx, t);
    if (s + 1 < NPH) grid_barrier(barr, s, bx, t);
  }
}

__global__ void __launch_bounds__(256)
k_step(int s, const float* feats, float* RZ, float* F, float* G4f, float* R,
       int* flags, float* GPb, float* XB, const int* Kptr, float* out, int mode) {
  __shared__ __align__(16) float LDSu[LDSF];
  do_step(s, feats, RZ, F, G4f, R, flags, GPb, XB, Kptr, out, mode, LDSu,
          blockIdx.x, threadIdx.x);
}

extern "C" void kernel_launch(void* const* d_in, const int* in_sizes, int n_in,
                              void* d_out, int out_size, void* d_ws, size_t ws_size,
                              hipStream_t stream) {
  const float* feats = (const float*)d_in[0];
  const int* Kptr = (n_in > 1) ? (const int*)d_in[1] : nullptr;
  float* ws = (float*)d_ws;
  float* RZ = ws;                        // 38400
  float* F  = ws + 38400;                // 4800
  float* G4f = ws + 43200;               // 6400 (1600 float4)
  float* R  = ws + 49600;                // 1600
  int* FLAGS = (int*)(ws + 51200);       // 16 ints (64 reserved)
  unsigned* BARR = (unsigned*)(ws + 51264);  // 576 uints (640 reserved)
  float* GPb = ws + 51904;               // 3 x 1024
  float* XB = ws + 54976;
  const size_t need2 = (size_t)(54976 + 3 * XSZ + 21 * 5 * XSZ) * 4;  // ~22.3 MB
  const size_t need1 = (size_t)(54976 + 24 * XSZ) * 4;                // ~5.1 MB
  const int mode = (ws_size >= need2) ? 2 : (ws_size >= need1) ? 1 : 0;

  hipMemsetAsync(ws + 51264, 0, 2560, stream);  // barrier counters

  float* outp = (float*)d_out;
  const float* fc = feats;
  int mv = mode;
  void* args[] = {(void*)&fc, (void*)&RZ, (void*)&F, (void*)&G4f, (void*)&R,
                  (void*)&FLAGS, (void*)&GPb, (void*)&XB, (void*)&Kptr,
                  (void*)&outp, (void*)&mv, (void*)&BARR};
  hipError_t err = hipLaunchCooperativeKernel(
      (const void*)k_solve, dim3(250, 1, 1), dim3(256, 1, 1), args, 0, stream);
  if (err != hipSuccess) {
    for (int s = 0; s < NPH; ++s)
      k_step<<<dim3(250), 256, 0, stream>>>(s, fc, RZ, F, G4f, R, FLAGS, GPb,
                                            XB, Kptr, outp, mv);
  }
}

// Round 12
// 641.147 us; speedup vs baseline: 1.3433x; 1.3433x over previous
//
#include <hip/hip_runtime.h>
#include <math.h>

#define N16 1600
#define M 32
#define XSZ 51200
#define LDSF 8448
#define WST 68
#define BIS_IT 28
#define EPSF 1e-12f
#define NPH 30   // 0 resize+zero | 1 prep | 2 degree | 3-12 MV1-10 | 13 gram |
                 // 14 apply | 15-24 MV11-20 | 25 gram | 26 apply | 27 MV21 |
                 // 28 gram | 29 rr

// ---------------- device-scope (L3-level) access helpers --------------------
__device__ __forceinline__ float ldg_dev(const float* p) {
  return __hip_atomic_load(p, __ATOMIC_RELAXED, __HIP_MEMORY_SCOPE_AGENT);
}
__device__ __forceinline__ void stg_dev(float* p, float v) {
  __hip_atomic_store(p, v, __ATOMIC_RELAXED, __HIP_MEMORY_SCOPE_AGENT);
}
__device__ __forceinline__ void stg_devi(int* p, int v) {
  __hip_atomic_store(p, v, __ATOMIC_RELAXED, __HIP_MEMORY_SCOPE_AGENT);
}

// ---------------- wave reductions -------------------------------------------
__device__ __forceinline__ float wred(float v) {
#pragma unroll
  for (int o = 32; o; o >>= 1) v += __shfl_xor(v, o, 64);
  return v;
}
__device__ __forceinline__ float wredmin(float v) {
#pragma unroll
  for (int o = 32; o; o >>= 1) v = fminf(v, __shfl_xor(v, o, 64));
  return v;
}
__device__ __forceinline__ float wredmax(float v) {
#pragma unroll
  for (int o = 32; o; o >>= 1) v = fmaxf(v, __shfl_xor(v, o, 64));
  return v;
}

// ---------------- spread monotonic grid barrier (250 blocks fixed) ----------
// 16 arrival counters 4 KB apart (distinct L3 sets/slices); master at
// barr[16*1024]; gen at barr[17*1024]. Monotonic, never reset: lane counter
// reaches (s+1)*quota when all its blocks arrived for step s.
__device__ __forceinline__ void grid_barrier(unsigned* barr, int s, int bx, int t) {
  __threadfence_block();
  __syncthreads();
  if (t == 0) {
    unsigned* gen = barr + 17 * 1024;
    const int lane = bx & 15;
    const unsigned quota = 15u + ((lane < 10) ? 1u : 0u);  // 250 = 10*16 + 6*15
    unsigned a = __hip_atomic_fetch_add(barr + lane * 1024, 1u, __ATOMIC_RELAXED,
                                        __HIP_MEMORY_SCOPE_AGENT);
    bool done = false;
    if (a + 1u == (unsigned)(s + 1) * quota) {
      unsigned m = __hip_atomic_fetch_add(barr + 16 * 1024, 1u, __ATOMIC_RELAXED,
                                          __HIP_MEMORY_SCOPE_AGENT);
      if (m + 1u == (unsigned)(s + 1) * 16u) {
        __hip_atomic_store(gen, (unsigned)(s + 1), __ATOMIC_RELAXED,
                           __HIP_MEMORY_SCOPE_AGENT);
        done = true;
      }
    }
    if (!done)
      while ((int)__hip_atomic_load(gen, __ATOMIC_RELAXED,
                                    __HIP_MEMORY_SCOPE_AGENT) <= s)
        __builtin_amdgcn_s_sleep(2);
  }
  __syncthreads();
}

// ---------------- phase: resize (bx<168) + zero (bx>=168) -------------------
__device__ void taps1d(int o, int* lo, int* hi, float* wsum, float w[8]) {
  int l = 4 * o - 2, h = 4 * o + 5;
  if (l < 0) l = 0;
  if (h > 159) h = 159;
  float c = 4.f * o + 1.5f, s = 0.f;
  for (int x = l; x <= h; ++x) {
    float ww = 1.f - fabsf((float)x - c) * 0.25f;
    w[x - l] = ww;
    s += ww;
  }
  *lo = l; *hi = h; *wsum = s;
}

__device__ void resize_phase(const float* __restrict__ in, float* __restrict__ rz,
                             int bx, int t) {
  int map = bx / 7;
  int o = (bx % 7) * 256 + t;
  if (o >= N16) return;
  int oy = o / 40, ox = o % 40;
  int ly, hy, lx, hx; float sy, sx; float wy[8], wx[8];
  taps1d(oy, &ly, &hy, &sy, wy);
  taps1d(ox, &lx, &hx, &sx, wx);
  const float* src = in + (size_t)map * 160 * 160;
  float acc = 0.f;
  for (int y = ly; y <= hy; ++y) {
    float a = 0.f;
    const float* row = src + y * 160;
    for (int x = lx; x <= hx; ++x) a += wx[x - lx] * row[x];
    acc += wy[y - ly] * a;
  }
  stg_dev(rz + map * N16 + o, acc / (sy * sx));
}

__device__ void zero_phase(float* __restrict__ XB, float* __restrict__ GPb,
                           int mode, int bx, int t) {
  int tid = (bx - 168) * 256 + t;
  const int stride = 82 * 256;
  float* base = XB + (size_t)(mode ? 3 : 1) * XSZ;
  size_t len = (size_t)(mode ? 21 : 3) * XSZ;
  for (size_t i = tid; i < len; i += stride) stg_dev(base + i, 0.f);
  for (int i = tid; i < 3072; i += stride) stg_dev(GPb + i, 0.f);
}

// ---------------- phase: prep (bx<23) ---------------------------------------
__device__ void prep_phase(const float* __restrict__ rz, float* __restrict__ F,
                           int* __restrict__ flags, float* LDSu, int bx, int t) {
  int* sp = (int*)LDSu;
  int* sn = sp + 256;
  if (bx < 16) {
    int b = bx >> 1, c = bx & 1;
    const float* m = rz + (b * 3 + c) * N16;
    int cp = 0, cn = 0;
    for (int o = t; o < N16; o += 256) {
      float v = m[o];
      cp += (v > 0.f);
      cn += (v < 0.f);
    }
    sp[t] = cp; sn[t] = cn;
    __syncthreads();
    for (int s = 128; s > 0; s >>= 1) {
      if (t < s) { sp[t] += sp[t + s]; sn[t] += sn[t + s]; }
      __syncthreads();
    }
    if (t == 0) stg_devi(flags + bx, (sp[0] == 0 || sn[0] == 0) ? 1 : 0);
  } else if (bx < 23) {
    int n = (bx - 16) * 256 + t;
    if (n < N16) {
      float x = rz[n], y = rz[N16 + n], z = rz[2 * N16 + n];
      float nrm = sqrtf(x * x + y * y + z * z);
      float s = 1.f / fmaxf(nrm, EPSF);
      stg_dev(F + n * 3 + 0, x * s);
      stg_dev(F + n * 3 + 1, y * s);
      stg_dev(F + n * 3 + 2, z * s);
    }
  }
}

// ---------------- phase: degree + G4 + X0 init (bx<100) ---------------------
__device__ void degree_phase(const float* __restrict__ F, float* __restrict__ R,
                             float* __restrict__ G4f, float* __restrict__ X0,
                             float* LDSu, int bx, int t) {
  float* Fl = LDSu;          // 4800
  float* red = LDSu + 4800;  // 256
  for (int s = t; s < 4800; s += 256) Fl[s] = F[s];
  __syncthreads();
  int rl = t >> 4, jt = t & 15;
  int i = bx * 16 + rl;
  float fx = Fl[i * 3], fy = Fl[i * 3 + 1], fz = Fl[i * 3 + 2];
  float s = 0.f;
  for (int j = jt; j < N16; j += 16) {
    float w = fx * Fl[j * 3] + fy * Fl[j * 3 + 1] + fz * Fl[j * 3 + 2];
    if (w > 0.f) s += w;
  }
  red[t] = s;
  __syncthreads();
  for (int st = 8; st > 0; st >>= 1) {
    if (jt < st) red[t] += red[t + st];
    __syncthreads();
  }
  if (jt == 0) {
    float d = red[t];
    if (d < EPSF) d = 1.f;
    float r = rsqrtf(d);
    stg_dev(R + i, r);
    stg_dev(G4f + i * 4 + 0, r * fx);
    stg_dev(G4f + i * 4 + 1, r * fy);
    stg_dev(G4f + i * 4 + 2, r * fz);
    stg_dev(G4f + i * 4 + 3, 0.f);
  }
  for (int e = t; e < 512; e += 256) {
    int n = bx * 16 + (e >> 5);
    int k = e & 31;
    unsigned u = ((unsigned)n * 2654435761u) ^ ((unsigned)k * 0x9E3779B9u);
    u = u * 1664525u + 1013904223u;
    u ^= u >> 16; u *= 2246822519u; u ^= u >> 13;
    stg_dev(X0 + n * M + k, ((float)(u >> 8) * (1.f / 8388608.f)) - 1.f);
  }
}

// ---------------- phase: MV -------------------------------------------------
__device__ void mv_phase(const float* __restrict__ F, const float4* __restrict__ G4,
                         const float* __restrict__ R, const float* __restrict__ Xin,
                         int cach, float* __restrict__ Xout,
                         float* __restrict__ Znext, int rb, int jp,
                         float* LDSu, int t) {
  float* XsT = LDSu;          // [32][WST]
  float* Ws  = LDSu + 2176;   // [32][WST]
  float* Red = LDSu + 4352;   // [4][1024]
  const int rg = t & 7, kg = (t >> 3) & 7, jg = t >> 6;
  const int i0 = rb * 32;
  const int jlo = jp * 320;
  const int il = t & 31;
  const float fx = F[(i0 + il) * 3], fy = F[(i0 + il) * 3 + 1],
              fz = F[(i0 + il) * 3 + 2];
  float acc[4][4];
#pragma unroll
  for (int r = 0; r < 4; ++r)
#pragma unroll
    for (int kk = 0; kk < 4; ++kk) acc[r][kk] = 0.f;

  for (int c = 0; c < 5; ++c) {
    const int jbase = jlo + c * 64;
    __syncthreads();
    if (cach) {
#pragma unroll
      for (int it = 0; it < 2; ++it) {
        int e = it * 256 + t;           // 0..511
        int row = e >> 3, q = e & 7;
        float4 v = *((const float4*)Xin + (size_t)(jbase + row) * 8 + q);
        XsT[(q * 4 + 0) * WST + row] = v.x;
        XsT[(q * 4 + 1) * WST + row] = v.y;
        XsT[(q * 4 + 2) * WST + row] = v.z;
        XsT[(q * 4 + 3) * WST + row] = v.w;
      }
    } else {
#pragma unroll
      for (int it = 0; it < 2; ++it) {
        int e = it * 256 + t;
        int row = e >> 3, q = e & 7;
        const float* p = Xin + (size_t)(jbase + row) * 32 + q * 4;
        float v0 = ldg_dev(p + 0);
        float v1 = ldg_dev(p + 1);
        float v2 = ldg_dev(p + 2);
        float v3 = ldg_dev(p + 3);
        XsT[(q * 4 + 0) * WST + row] = v0;
        XsT[(q * 4 + 1) * WST + row] = v1;
        XsT[(q * 4 + 2) * WST + row] = v2;
        XsT[(q * 4 + 3) * WST + row] = v3;
      }
    }
#pragma unroll
    for (int it = 0; it < 8; ++it) {
      int jl = it * 8 + (t >> 5);
      float4 g = G4[jbase + jl];
      Ws[il * WST + jl] = fmaxf(fx * g.x + fy * g.y + fz * g.z, 0.f);
    }
    __syncthreads();
#pragma unroll
    for (int q = 0; q < 4; ++q) {
      const int jq = (jg * 4 + q) * 4;
      float4 wv[4], xv[4];
#pragma unroll
      for (int r = 0; r < 4; ++r)
        wv[r] = *(const float4*)&Ws[(rg + 8 * r) * WST + jq];
#pragma unroll
      for (int kk = 0; kk < 4; ++kk)
        xv[kk] = *(const float4*)&XsT[(kg + 8 * kk) * WST + jq];
#pragma unroll
      for (int r = 0; r < 4; ++r)
#pragma unroll
        for (int kk = 0; kk < 4; ++kk)
          acc[r][kk] += wv[r].x * xv[kk].x + wv[r].y * xv[kk].y +
                        wv[r].z * xv[kk].z + wv[r].w * xv[kk].w;
    }
  }
  __syncthreads();
#pragma unroll
  for (int r = 0; r < 4; ++r)
#pragma unroll
    for (int kk = 0; kk < 4; ++kk)
      Red[jg * 1024 + (rg + 8 * r) * 32 + (kg + 8 * kk)] = acc[r][kk];
  __syncthreads();
#pragma unroll
  for (int it = 0; it < 4; ++it) {
    int o = it * 256 + t;
    int ilw = o >> 5, k = o & 31;
    int gi = i0 + ilw;
    float sv = Red[o] + Red[1024 + o] + Red[2048 + o] + Red[3072 + o];
    float val = 0.5f * R[gi] * sv;
    if (jp == 0) {
      float xi = cach ? Xin[(size_t)gi * 32 + k] : ldg_dev(Xin + (size_t)gi * 32 + k);
      val += 0.5f * xi;
    }
    atomicAdd(Xout + (size_t)gi * 32 + k, val);
  }
  if (Znext && jp == 1) {
#pragma unroll
    for (int it = 0; it < 4; ++it)
      stg_dev(Znext + (size_t)i0 * 32 + it * 256 + t, 0.f);
  }
}

// ---------------- phase: gram (bx<25) ---------------------------------------
__device__ void gram_phase(const float* __restrict__ Xa, const float* __restrict__ Xb,
                           float* __restrict__ GP, float* LDSu, int bx, int t) {
  float* sA = LDSu;
  float* sB = LDSu + 2048;
  int j0 = bx * 64;
  for (int s = t; s < 64 * M; s += 256) {
    size_t idx = (size_t)j0 * M + s;
    sA[s] = ldg_dev(Xa + idx);
    sB[s] = ldg_dev(Xb + idx);
  }
  __syncthreads();
  for (int s = 0; s < 4; ++s) {
    int e = s * 256 + t;
    int a = e >> 5, b = e & 31;
    float sum = 0.f;
    for (int jl = 0; jl < 64; ++jl) sum += sA[jl * M + a] * sB[jl * M + b];
    atomicAdd(GP + e, sum);
  }
}

// ---------------- phase: apply (bx<200): chol + register trisolve -----------
__device__ void apply_phase(const float* __restrict__ GP,
                            const float* __restrict__ Xin,
                            float* __restrict__ Xout, float* LDSu, int bx, int t) {
  float* Gm = LDSu;  // 32*33
  for (int e = t; e < 1024; e += 256)
    Gm[(e >> 5) * 33 + (e & 31)] = ldg_dev(GP + e);
  const int r = t >> 5, l = t & 31;
  const int row = bx * 8 + r;
  float x = ldg_dev(Xin + (size_t)row * M + l);
  __syncthreads();
  for (int k = 0; k < 32; ++k) {
    if (t == 0) Gm[k * 33 + k] = sqrtf(fmaxf(Gm[k * 33 + k], 1e-30f));
    __syncthreads();
    float piv = Gm[k * 33 + k];
    if (t > k && t < 32) Gm[t * 33 + k] /= piv;
    __syncthreads();
    for (int e = t; e < 1024; e += 256) {
      int i = e >> 5, j = e & 31;
      if (i > k && j > k && j <= i) Gm[i * 33 + j] -= Gm[i * 33 + k] * Gm[j * 33 + k];
    }
    __syncthreads();
  }
  const int half = t & 32;
  float y = 0.f;
  for (int k = 0; k < 32; ++k) {
    float gkl = Gm[k * 33 + l];
    float contrib = (l < k) ? y * gkl : 0.f;
#pragma unroll
    for (int o = 16; o; o >>= 1) contrib += __shfl_xor(contrib, o, 64);
    float xk = __shfl(x, half + k, 64);
    float yk = (xk - contrib) / Gm[k * 33 + k];
    if (l == k) y = yk;
  }
  stg_dev(Xout + (size_t)row * M + l, y);
}

// ---------------- phase: rr (bx==0) -----------------------------------------
__device__ void rr_phase(const float* __restrict__ GP,
                         const int* __restrict__ flags,
                         const int* __restrict__ Kptr,
                         float* __restrict__ out, float* Ph, int t) {
  float* Bs   = Ph;
  float* part = Ph + 1056;
  float* vvs  = Ph + 2080;
  float* uus  = Ph + 2112;
  float* dd   = Ph + 2144;
  float* ee   = Ph + 2176;
  float* ee2  = Ph + 2208;
  float* evs  = Ph + 2240;
  float* shs  = Ph + 2272;
  for (int e = t; e < 1024; e += 256) part[e] = ldg_dev(GP + e);
  __syncthreads();
  for (int e = t; e < 1024; e += 256) {
    int i = e >> 5, j = e & 31;
    Bs[i * 33 + j] = 0.5f * (part[e] + part[j * 32 + i]);
  }
  __syncthreads();
  for (int k = 0; k <= 29; ++k) {
    const int m = 31 - k;
    if (t < 64) {
      float xi = (t < m) ? Bs[(k + 1 + t) * 33 + k] : 0.f;
      float nx2 = wred(xi * xi);
      if (t == 0) { shs[0] = nx2; shs[1] = Bs[(k + 1) * 33 + k]; }
    }
    __syncthreads();
    float nx2 = shs[0], x0 = shs[1];
    if (nx2 < 1e-28f) {
      if (t == 0) ee[k] = x0;
      __syncthreads();
      continue;
    }
    if (t < 32) {
      float alpha = (x0 >= 0.f) ? -sqrtf(nx2) : sqrtf(nx2);
      float h = nx2 - alpha * x0;
      float xi = (t < m) ? Bs[(k + 1 + t) * 33 + k] : 0.f;
      float vi = (t == 0) ? (xi - alpha) : xi;
      vvs[t] = (t < m) ? vi : 0.f;
      if (t == 0) { ee[k] = alpha; shs[2] = h; }
    }
    __syncthreads();
    {
      int i = t >> 3, s = t & 7;
      float p = 0.f;
      if (i < m) {
        const float* rowp = &Bs[(k + 1 + i) * 33 + (k + 1)];
        for (int j = s; j < m; j += 8) p += rowp[j] * vvs[j];
      }
      part[t] = p;
    }
    __syncthreads();
    if (t < 64) {
      float h = shs[2];
      float pi = 0.f;
      if (t < 32) {
#pragma unroll
        for (int s = 0; s < 8; ++s) pi += part[t * 8 + s];
        pi /= h;
      }
      float vip = (t < 32) ? vvs[t] * pi : 0.f;
      float vp = wred(vip);
      float Kc = vp / (2.f * h);
      if (t < 32) uus[t] = (t < m) ? (pi - Kc * vvs[t]) : 0.f;
    }
    __syncthreads();
    for (int e = t; e < 1024; e += 256) {
      int i = e >> 5, j = e & 31;
      if (i < m && j < m)
        Bs[(k + 1 + i) * 33 + (k + 1 + j)] -= vvs[i] * uus[j] + uus[i] * vvs[j];
    }
    __syncthreads();
  }
  if (t < 32) dd[t] = Bs[t * 33 + t];
  if (t == 0) { ee[30] = Bs[31 * 33 + 30]; ee[31] = 0.f; }
  __syncthreads();
  if (t < 32) ee2[t] = (t < 31) ? ee[t] * ee[t] : 0.f;
  __syncthreads();
  if (t < 64) {
    int tt = t & 31;
    float di = dd[tt];
    float r = 0.f;
    if (tt > 0) r += fabsf(ee[tt - 1]);
    if (tt < 31) r += fabsf(ee[tt]);
    float lo = wredmin(di - r);
    float hi = wredmax(di + r);
    if (t == 0) { shs[0] = lo - 1e-6f; shs[1] = hi + 1e-6f; }
  }
  __syncthreads();
  if (t < 32) {
    float a = shs[0], b = shs[1];
    for (int it = 0; it < BIS_IT; ++it) {
      float mid = 0.5f * (a + b);
      float q = dd[0] - mid;
      int cnt = (q < 0.f) ? 1 : 0;
#pragma unroll
      for (int i = 1; i < 32; ++i) {
        float den = q;
        float ad = fabsf(den);
        den = (ad < 1e-30f) ? ((den < 0.f) ? -1e-30f : 1e-30f) : den;
        q = dd[i] - mid - ee2[i - 1] * __builtin_amdgcn_rcpf(den);
        cnt += (q < 0.f) ? 1 : 0;
      }
      if (cnt <= t) a = mid; else b = mid;
    }
    evs[t] = 0.5f * (a + b);
  }
  __syncthreads();
  if (t == 0) {
    int K = Kptr ? *Kptr : 10;
    if (K < 1) K = 10;
    if (K > 32) K = 32;
    float t12 = 0.f, t13 = 0.f, t23 = 0.f;
    for (int b = 0; b < 8; ++b) {
      float f1 = flags[b * 2 + 0] ? 1.f : 0.f;
      float f2 = flags[b * 2 + 1] ? 1.f : 0.f;
      for (int k = 0; k < K; ++k) {
        float v1 = (k == 0) ? 0.f : (k == 1 ? f1 : 1.f);
        float v2 = (k == 0) ? 0.f : (k == 1 ? f2 : 1.f);
        float m3 = 2.f - 2.f * evs[31 - k];
        t12 += (v1 - v2) * (v1 - v2);
        t13 += (v1 - m3) * (v1 - m3);
        t23 += (v2 - m3) * (v2 - m3);
      }
    }
    out[0] = 5.f * (t12 + t13 + t23) / (8.f * (float)K);
  }
}

// ---------------- unified step dispatcher -----------------------------------
__device__ __forceinline__ float* bbuf(float* XB, int mode, int m) {
  return XB + (size_t)(mode ? (2 + m) : (1 + m % 3)) * XSZ;
}

__device__ void do_step(int s, const float* feats, float* RZ, float* F,
                        float* G4f, float* R, int* flags, float* GPb, float* XB,
                        const int* Kptr, float* out, int mode,
                        float* LDSu, int bx, int t) {
  float* X0  = XB;
  float* XV1 = XB + (size_t)(mode ? 1 : 0) * XSZ;
  float* XV2 = XB + (size_t)(mode ? 2 : 0) * XSZ;
  const float4* G4 = (const float4*)G4f;
  if (s == 0) {
    if (bx < 168) resize_phase(feats, RZ, bx, t);
    else zero_phase(XB, GPb, mode, bx, t);
    return;
  }
  if (s == 1) { prep_phase(RZ, F, flags, LDSu, bx, t); return; }
  if (s == 2) { if (bx < 100) degree_phase(F, R, G4f, X0, LDSu, bx, t); return; }
  if (s == 13) { if (bx < 25) gram_phase(bbuf(XB, mode, 10), bbuf(XB, mode, 10), GPb, LDSu, bx, t); return; }
  if (s == 14) { if (bx < 200) apply_phase(GPb, bbuf(XB, mode, 10), XV1, LDSu, bx, t); return; }
  if (s == 25) { if (bx < 25) gram_phase(bbuf(XB, mode, 20), bbuf(XB, mode, 20), GPb + 1024, LDSu, bx, t); return; }
  if (s == 26) { if (bx < 200) apply_phase(GPb + 1024, bbuf(XB, mode, 20), XV2, LDSu, bx, t); return; }
  if (s == 28) { if (bx < 25) gram_phase(XV2, bbuf(XB, mode, 21), GPb + 2048, LDSu, bx, t); return; }
  if (s == 29) { if (bx == 0) rr_phase(GPb + 2048, flags, Kptr, out, LDSu, t); return; }
  int m;
  if (s >= 3 && s <= 12) m = s - 2;
  else if (s >= 15 && s <= 24) m = s - 4;
  else m = 21;
  const float* Xin =
      (m == 1) ? X0 : (m == 11) ? XV1 : (m == 21) ? XV2 : bbuf(XB, mode, m - 1);
  float* Xout = bbuf(XB, mode, m);
  float* Znext = (mode == 0 && m < 21) ? bbuf(XB, 0, m + 1) : nullptr;
  mv_phase(F, G4, R, Xin, (mode == 1), Xout, Znext, bx / 5, bx % 5, LDSu, t);
}

__global__ void __launch_bounds__(256)
k_solve(const float* feats, float* RZ, float* F, float* G4f, float* R,
        int* flags, float* GPb, float* XB, const int* Kptr, float* out,
        int mode, unsigned* barr) {
  __shared__ __align__(16) float LDSu[LDSF];
  const int bx = blockIdx.x, t = threadIdx.x;
  for (int s = 0; s < NPH; ++s) {
    do_step(s, feats, RZ, F, G4f, R, flags, GPb, XB, Kptr, out, mode, LDSu, bx, t);
    if (s + 1 < NPH) grid_barrier(barr, s, bx, t);
  }
}

__global__ void __launch_bounds__(256)
k_step(int s, const float* feats, float* RZ, float* F, float* G4f, float* R,
       int* flags, float* GPb, float* XB, const int* Kptr, float* out, int mode) {
  __shared__ __align__(16) float LDSu[LDSF];
  do_step(s, feats, RZ, F, G4f, R, flags, GPb, XB, Kptr, out, mode, LDSu,
          blockIdx.x, threadIdx.x);
}

extern "C" void kernel_launch(void* const* d_in, const int* in_sizes, int n_in,
                              void* d_out, int out_size, void* d_ws, size_t ws_size,
                              hipStream_t stream) {
  const float* feats = (const float*)d_in[0];
  const int* Kptr = (n_in > 1) ? (const int*)d_in[1] : nullptr;
  float* ws = (float*)d_ws;
  float* RZ = ws;                        // 38400
  float* F  = ws + 38400;                // 4800
  float* G4f = ws + 43200;               // 6400 (1600 float4)
  float* R  = ws + 49600;                // 1600
  int* FLAGS = (int*)(ws + 51200);       // 16 ints (64 reserved)
  unsigned* BARR = (unsigned*)(ws + 51264);  // 18*1024 uints (4KB-strided)
  float* GPb = ws + 51264 + 18 * 1024;   // 3 x 1024
  float* XB = ws + 51264 + 18 * 1024 + 3072;
  const size_t need1 = (size_t)(51264 + 18 * 1024 + 3072 + 24 * XSZ) * 4;  // ~5.2 MB
  const int mode = (ws_size >= need1) ? 1 : 0;

  hipMemsetAsync(BARR, 0, 18 * 1024 * 4, stream);  // barrier counters

  float* outp = (float*)d_out;
  const float* fc = feats;
  int mv = mode;
  void* args[] = {(void*)&fc, (void*)&RZ, (void*)&F, (void*)&G4f, (void*)&R,
                  (void*)&FLAGS, (void*)&GPb, (void*)&XB, (void*)&Kptr,
                  (void*)&outp, (void*)&mv, (void*)&BARR};
  hipError_t err = hipLaunchCooperativeKernel(
      (const void*)k_solve, dim3(250, 1, 1), dim3(256, 1, 1), args, 0, stream);
  if (err != hipSuccess) {
    for (int s = 0; s < NPH; ++s)
      k_step<<<dim3(250), 256, 0, stream>>>(s, fc, RZ, F, G4f, R, FLAGS, GPb,
                                            XB, Kptr, outp, mv);
  }
}